// Round 5
// baseline (1415.076 us; speedup 1.0000x reference)
//
#include <hip/hip_runtime.h>

#define BATCH 32
#define NMAT 1024
#define NBLK 256              // one block per CU -> all co-resident
#define NWAVE 16
#define N_ITERS 20
#define SHIFT 5.0f            // E stores t' = exp(-10*D + 5); e^5 cancels in t/S

typedef _Float16 h8 __attribute__((ext_vector_type(8)));
typedef float    f8 __attribute__((ext_vector_type(8)));

__device__ __forceinline__ float wave_allsum(float s) {
#pragma unroll
    for (int off = 1; off < 64; off <<= 1) s += __shfl_xor(s, off, 64);
    return s;
}

__device__ __forceinline__ float4 f4add(float4 a, float4 b) {
    return make_float4(a.x + b.x, a.y + b.y, a.z + b.z, a.w + b.w);
}

// Workspace is poisoned between runs: zero the per-iteration arrival counters.
__global__ void init_ctr(unsigned* __restrict__ ctr) { ctr[threadIdx.x] = 0u; }

// In-block reduction of per-wave column partials (by value, conflict-free f4).
__device__ __forceinline__ float stage_colsum(f8 a0, f8 a1, float4* sbuf,
                                              int wave, int lane, int tid) {
    const int w4 = wave & 3;
    const float4 m0 = make_float4(a0[0], a0[1], a0[2], a0[3]);
    const float4 m1 = make_float4(a0[4], a0[5], a0[6], a0[7]);
    const float4 m2 = make_float4(a1[0], a1[1], a1[2], a1[3]);
    const float4 m3 = make_float4(a1[4], a1[5], a1[6], a1[7]);
    __syncthreads();                      // previous readers of sbuf are done
    const int i0 = (w4 << 8) + lane;
    if (wave < 4) {
        sbuf[i0]       = m0;
        sbuf[i0 + 64]  = m1;
        sbuf[i0 + 128] = m2;
        sbuf[i0 + 192] = m3;
    }
    __syncthreads();
#pragma unroll
    for (int g = 1; g < 4; ++g) {         // 3 serialized add rounds
        if ((wave >> 2) == g) {
            sbuf[i0]       = f4add(sbuf[i0],       m0);
            sbuf[i0 + 64]  = f4add(sbuf[i0 + 64],  m1);
            sbuf[i0 + 128] = f4add(sbuf[i0 + 128], m2);
            sbuf[i0 + 192] = f4add(sbuf[i0 + 192], m3);
        }
        __syncthreads();
    }
    const int rem = tid & 511, lt = rem >> 3, ut = rem & 7;
    const int ht = ((tid >> 9) << 1) + (ut >> 2), rt = ut & 3;
    const float* bf = (const float*)sbuf;
    float cs = 0.f;
#pragma unroll
    for (int w = 0; w < 4; ++w) cs += bf[(((w << 8) + (ht << 6) + lt) << 2) + rt];
    return cs;
}

// Device-scope grid barrier: per-iteration counter slot (no reset, no ABA).
__device__ __forceinline__ void grid_barrier(unsigned* c, int tid) {
    __syncthreads();
    if (tid == 0) {
        __threadfence();
        __hip_atomic_fetch_add(c, 1u, __ATOMIC_RELEASE, __HIP_MEMORY_SCOPE_AGENT);
        int guard = 0;
        while (__hip_atomic_load(c, __ATOMIC_RELAXED, __HIP_MEMORY_SCOPE_AGENT) < NBLK &&
               guard < (1 << 24)) {       // ~1 s bail-out: fail, don't hang
            __builtin_amdgcn_s_sleep(2);
            ++guard;
        }
        (void)__hip_atomic_load(c, __ATOMIC_ACQUIRE, __HIP_MEMORY_SCOPE_AGENT);
    }
    __syncthreads();
}

// ---- per-row helpers: everything via fp16 h-vectors, constant indices ----
#define EXP8(H, DA, DB)                                                        \
    (H)[0] = (_Float16)__expf(fmaf((DA).x, -10.f, SHIFT));                     \
    (H)[1] = (_Float16)__expf(fmaf((DA).y, -10.f, SHIFT));                     \
    (H)[2] = (_Float16)__expf(fmaf((DA).z, -10.f, SHIFT));                     \
    (H)[3] = (_Float16)__expf(fmaf((DA).w, -10.f, SHIFT));                     \
    (H)[4] = (_Float16)__expf(fmaf((DB).x, -10.f, SHIFT));                     \
    (H)[5] = (_Float16)__expf(fmaf((DB).y, -10.f, SHIFT));                     \
    (H)[6] = (_Float16)__expf(fmaf((DB).z, -10.f, SHIFT));                     \
    (H)[7] = (_Float16)__expf(fmaf((DB).w, -10.f, SHIFT));

#define SUM8(H) ((float)(H)[0] + (float)(H)[1] + (float)(H)[2] + (float)(H)[3] \
               + (float)(H)[4] + (float)(H)[5] + (float)(H)[6] + (float)(H)[7])

#define DOT8(H, A, B)                                                          \
    ((float)(H)[0]*(A).x + (float)(H)[1]*(A).y + (float)(H)[2]*(A).z +         \
     (float)(H)[3]*(A).w + (float)(H)[4]*(B).x + (float)(H)[5]*(B).y +         \
     (float)(H)[6]*(B).z + (float)(H)[7]*(B).w)

#define ACC8(CA, H, RS)                                                        \
    _Pragma("unroll")                                                          \
    for (int q = 0; q < 8; ++q) (CA)[q] = fmaf((float)(H)[q], (RS), (CA)[q]);

#define ACCQ8(QA, H, RS)                                                       \
    _Pragma("unroll")                                                          \
    for (int q = 0; q < 8; ++q) {                                              \
        const float tq = (float)(H)[q];                                        \
        (QA)[q] = fmaf(tq * ((SHIFT - __logf(tq)) * 0.1f), (RS), (QA)[q]);     \
    }

// Build: read D row (HBM, once), pack fp16; rows 0..3 also stored to LDS.
#define BUILD_ROW(RR, STORELDS)                                                \
    {                                                                          \
        const float4* D4 = (const float4*)(D + ((rbase + (RR)) << 10));        \
        const float4 d0 = D4[2 * lane], d1 = D4[2 * lane + 1];                 \
        h8 h0; EXP8(h0, d0, d1)                                                \
        const float4 d2 = D4[2 * (lane + 64)], d3 = D4[2 * (lane + 64) + 1];   \
        h8 h1; EXP8(h1, d2, d3)                                                \
        if (STORELDS) {                                                        \
            h8* Er = (h8*)eL[(wave << 2) + (RR)];                              \
            Er[lane] = h0; Er[lane + 64] = h1;                                 \
        }                                                                      \
        float s = SUM8(h0) + SUM8(h1);                                         \
        s = wave_allsum(s);                                                    \
        const float rs = __builtin_amdgcn_rcpf(s);                             \
        ACC8(ca0, h0, rs) ACC8(ca1, h1, rs)                                    \
        __builtin_amdgcn_sched_barrier(0);                                     \
    }

// Iter row from LDS-resident fp16 E.
#define ITER_LROW(K)                                                           \
    {                                                                          \
        const h8* Er = (const h8*)eL[(wave << 2) + (K)];                       \
        const h8 h0 = Er[lane], h1 = Er[lane + 64];                            \
        const float4 g0 = evb4[lane],        g1 = evb4[64 + lane];             \
        const float4 g2 = evb4[128 + lane],  g3 = evb4[192 + lane];            \
        float s = DOT8(h0, g0, g1) + DOT8(h1, g2, g3);                         \
        s = wave_allsum(s);                                                    \
        const float rs = __builtin_amdgcn_rcpf(s);                             \
        ACC8(ca0, h0, rs) ACC8(ca1, h1, rs)                                    \
        if (last) { ACCQ8(qa0, h0, rs) ACCQ8(qa1, h1, rs) }                    \
        __builtin_amdgcn_sched_barrier(0);                                     \
    }

// Iter row recomputed from D (L3-resident: 128 MB < 256 MB LLC).
#define ITER_DROW(RR)                                                          \
    {                                                                          \
        const float4* D4 = (const float4*)(D + ((rbase + (RR)) << 10));        \
        const float4 d0 = D4[2 * lane], d1 = D4[2 * lane + 1];                 \
        h8 h0; EXP8(h0, d0, d1)                                                \
        const float4 d2 = D4[2 * (lane + 64)], d3 = D4[2 * (lane + 64) + 1];   \
        h8 h1; EXP8(h1, d2, d3)                                                \
        const float4 g0 = evb4[lane],        g1 = evb4[64 + lane];             \
        const float4 g2 = evb4[128 + lane],  g3 = evb4[192 + lane];            \
        float s = DOT8(h0, g0, g1) + DOT8(h1, g2, g3);                         \
        s = wave_allsum(s);                                                    \
        const float rs = __builtin_amdgcn_rcpf(s);                             \
        ACC8(ca0, h0, rs) ACC8(ca1, h1, rs)                                    \
        if (last) { ACCQ8(qa0, h0, rs) ACCQ8(qa1, h1, rs) }                    \
        __builtin_amdgcn_sched_barrier(0);                                     \
    }

// Working set redesigned to fit the 64-VGPR budget this toolchain pins:
// no persistent E registers. 4 rows/wave in LDS fp16; 4 rows/wave recomputed
// from L3-resident D each iteration. Peak live ~56 regs.
__global__ void __attribute__((amdgpu_flat_work_group_size(1024, 1024)))
__attribute__((amdgpu_waves_per_eu(4, 4)))
sinkhorn_persist(const float* __restrict__ D, float* __restrict__ Pg,
                 float* __restrict__ Qg, unsigned* __restrict__ ctr,
                 float* __restrict__ out) {
    __shared__ __align__(16) _Float16 eL[NWAVE * 4][NMAT];        // 128 KB
    __shared__ float4 sbuf[1024];                                 // 16 KB
    __shared__ float4 evb4[NMAT / 4];                             // 4 KB (permuted)
    float* evb = (float*)evb4;

    const int b = blockIdx.x;
    const int bb = b >> 3, slab = b & 7;       // batch, row-slab within batch
    const int tid = threadIdx.x;
    const int wave = tid >> 6, lane = tid & 63;
    const size_t rbase = ((size_t)bb << 10) + (slab << 7) + (wave << 3);

    f8 ca0, ca1, qa0, qa1;

#pragma unroll 1
    for (int it = 0; it < N_ITERS; ++it) {
        const bool last = (it == N_ITERS - 1);
#pragma unroll
        for (int q = 0; q < 8; ++q) { ca0[q] = 0.f; ca1[q] = 0.f; }
        if (last) {
#pragma unroll
            for (int q = 0; q < 8; ++q) { qa0[q] = 0.f; qa1[q] = 0.f; }
        }

        if (it == 0) {
            // Build: read D (HBM once), stage rows 0..3 as fp16 in LDS,
            // iteration 1 (ev == 1) on the fly.
            BUILD_ROW(0, 1)
            BUILD_ROW(1, 1)
            BUILD_ROW(2, 1)
            BUILD_ROW(3, 1)
            BUILD_ROW(4, 0)
            BUILD_ROW(5, 0)
            BUILD_ROW(6, 0)
            BUILD_ROW(7, 0)
        } else {
            ITER_LROW(0)
            ITER_LROW(1)
            ITER_LROW(2)
            ITER_LROW(3)
            ITER_DROW(4)
            ITER_DROW(5)
            ITER_DROW(6)
            ITER_DROW(7)
        }

        // Block-level column reduction -> one 4 KB partial per block.
        const int par = it & 1;   // parity double-buffer (no 2nd barrier needed)
        const float cs = stage_colsum(ca0, ca1, sbuf, wave, lane, tid);
        Pg[((par * NBLK + b) << 10) + tid] = cs;
        if (last) {
            const float qs = stage_colsum(qa0, qa1, sbuf, wave, lane, tid);
            Qg[(b << 10) + tid] = qs;
            if (b == 0 && tid == 0) out[0] = 0.f;   // arm final atomics
        }

        grid_barrier(&ctr[it], tid);

        if (!last) {
            // Redundant per-block ev: gather this batch's 8 partials.
            const float* Pb = Pg + ((par * NBLK + (bb << 3)) << 10) + tid;
            float s8 = 0.f;
#pragma unroll
            for (int j = 0; j < 8; ++j) s8 += Pb[j << 10];
            const float evv = 1.0f / s8;
            const int rem = tid & 511, lt = rem >> 3, ut = rem & 7;
            const int ht = ((tid >> 9) << 1) + (ut >> 2), rt = ut & 3;
            evb[(((ht << 6) + lt) << 2) + rt] = evv;
            __syncthreads();               // evb ready for next iteration
        } else if (slab == 0) {
            // loss = mean_b sum_m (sum_j Q[j][m]) / (sum_j P[j][m])
            const float* Pb = Pg + ((par * NBLK + (bb << 3)) << 10) + tid;
            const float* Qb = Qg + (((bb << 3)) << 10) + tid;
            float s8 = 0.f, q8 = 0.f;
#pragma unroll
            for (int j = 0; j < 8; ++j) { s8 += Pb[j << 10]; q8 += Qb[j << 10]; }
            float c = q8 / s8;
            c = wave_allsum(c);
            if (lane == 0) ((float*)sbuf)[wave] = c;
            __syncthreads();
            if (tid == 0) {
                float tot = 0.f;
#pragma unroll
                for (int w = 0; w < NWAVE; ++w) tot += ((float*)sbuf)[w];
                atomicAdd(out, tot * (1.0f / (float)BATCH));
            }
        }
    }
}

extern "C" void kernel_launch(void* const* d_in, const int* in_sizes, int n_in,
                              void* d_out, int out_size, void* d_ws, size_t ws_size,
                              hipStream_t stream) {
    const float* D = (const float*)d_in[0];
    float* out = (float*)d_out;

    unsigned* ctr = (unsigned*)d_ws;                    // 64 slots (zeroed below)
    float* Pg = (float*)((char*)d_ws + 1024);           // [2][256][1024] f32 = 2 MB
    float* Qg = Pg + 2 * NBLK * NMAT;                   // [256][1024] f32 = 1 MB

    init_ctr<<<1, 64, 0, stream>>>(ctr);
    sinkhorn_persist<<<NBLK, NWAVE * 64, 0, stream>>>(D, Pg, Qg, ctr, out);
}

// Round 6
// 1137.562 us; speedup vs baseline: 1.2440x; 1.2440x over previous
//
#include <hip/hip_runtime.h>

#define BATCH 32
#define NMAT 1024
#define NBLK 256              // one block per CU -> all co-resident
#define NWAVE 16
#define N_ITERS 20
#define SHIFT 5.0f            // E stores t' = exp(-10*D + 5); e^5 cancels in t/S

typedef _Float16 h8 __attribute__((ext_vector_type(8)));
typedef float    f8 __attribute__((ext_vector_type(8)));

__device__ __forceinline__ float wave_allsum(float s) {
#pragma unroll
    for (int off = 1; off < 64; off <<= 1) s += __shfl_xor(s, off, 64);
    return s;
}

__device__ __forceinline__ float4 f4add(float4 a, float4 b) {
    return make_float4(a.x + b.x, a.y + b.y, a.z + b.z, a.w + b.w);
}

// Coherent (write-through / L2-bypassing) accessors for cross-block data.
// RELAXED+AGENT -> plain sc-bit load/store, NO buffer_wbl2 / buffer_inv.
__device__ __forceinline__ void cstore(float* p, float v) {
    __hip_atomic_store(p, v, __ATOMIC_RELAXED, __HIP_MEMORY_SCOPE_AGENT);
}
__device__ __forceinline__ float cload(const float* p) {
    return __hip_atomic_load((const float*)p, __ATOMIC_RELAXED, __HIP_MEMORY_SCOPE_AGENT);
}

// Workspace is poisoned between runs: zero the per-iteration arrival counters
// with coherent stores (visible to all XCDs without cache flushes).
__global__ void init_ctr(unsigned* __restrict__ ctr) {
    __hip_atomic_store(&ctr[threadIdx.x], 0u, __ATOMIC_RELAXED, __HIP_MEMORY_SCOPE_AGENT);
}

// In-block reduction of per-wave column partials (by value, conflict-free f4).
__device__ __forceinline__ float stage_colsum(f8 a0, f8 a1, float4* sbuf,
                                              int wave, int lane, int tid) {
    const int w4 = wave & 3;
    const float4 m0 = make_float4(a0[0], a0[1], a0[2], a0[3]);
    const float4 m1 = make_float4(a0[4], a0[5], a0[6], a0[7]);
    const float4 m2 = make_float4(a1[0], a1[1], a1[2], a1[3]);
    const float4 m3 = make_float4(a1[4], a1[5], a1[6], a1[7]);
    __syncthreads();                      // previous readers of sbuf are done
    const int i0 = (w4 << 8) + lane;
    if (wave < 4) {
        sbuf[i0]       = m0;
        sbuf[i0 + 64]  = m1;
        sbuf[i0 + 128] = m2;
        sbuf[i0 + 192] = m3;
    }
    __syncthreads();
#pragma unroll
    for (int g = 1; g < 4; ++g) {         // 3 serialized add rounds
        if ((wave >> 2) == g) {
            sbuf[i0]       = f4add(sbuf[i0],       m0);
            sbuf[i0 + 64]  = f4add(sbuf[i0 + 64],  m1);
            sbuf[i0 + 128] = f4add(sbuf[i0 + 128], m2);
            sbuf[i0 + 192] = f4add(sbuf[i0 + 192], m3);
        }
        __syncthreads();
    }
    const int rem = tid & 511, lt = rem >> 3, ut = rem & 7;
    const int ht = ((tid >> 9) << 1) + (ut >> 2), rt = ut & 3;
    const float* bf = (const float*)sbuf;
    float cs = 0.f;
#pragma unroll
    for (int w = 0; w < 4; ++w) cs += bf[(((w << 8) + (ht << 6) + lt) << 2) + rt];
    return cs;
}

// Fence-free grid barrier. All cross-block data moves via coherent (sc-bit)
// accesses, so NO __threadfence (buffer_wbl2) / acquire (buffer_inv) needed:
// per-wave vmcnt(0) guarantees our coherent stores reached the coherence
// point before the arrival add; polls read the coherence point directly.
__device__ __forceinline__ void grid_barrier(unsigned* c, int tid) {
    asm volatile("s_waitcnt vmcnt(0)" ::: "memory");  // drain this wave's stores
    __syncthreads();                                   // all waves drained
    if (tid == 0) {
        __hip_atomic_fetch_add(c, 1u, __ATOMIC_RELAXED, __HIP_MEMORY_SCOPE_AGENT);
        int guard = 0;
        while (__hip_atomic_load(c, __ATOMIC_RELAXED, __HIP_MEMORY_SCOPE_AGENT) < NBLK &&
               guard < (1 << 24)) {       // ~1 s bail-out: fail, don't hang
            __builtin_amdgcn_s_sleep(2);
            ++guard;
        }
    }
    __syncthreads();
}

// ---- per-row helpers: everything via fp16 h-vectors, constant indices ----
#define EXP8(H, DA, DB)                                                        \
    (H)[0] = (_Float16)__expf(fmaf((DA).x, -10.f, SHIFT));                     \
    (H)[1] = (_Float16)__expf(fmaf((DA).y, -10.f, SHIFT));                     \
    (H)[2] = (_Float16)__expf(fmaf((DA).z, -10.f, SHIFT));                     \
    (H)[3] = (_Float16)__expf(fmaf((DA).w, -10.f, SHIFT));                     \
    (H)[4] = (_Float16)__expf(fmaf((DB).x, -10.f, SHIFT));                     \
    (H)[5] = (_Float16)__expf(fmaf((DB).y, -10.f, SHIFT));                     \
    (H)[6] = (_Float16)__expf(fmaf((DB).z, -10.f, SHIFT));                     \
    (H)[7] = (_Float16)__expf(fmaf((DB).w, -10.f, SHIFT));

#define SUM8(H) ((float)(H)[0] + (float)(H)[1] + (float)(H)[2] + (float)(H)[3] \
               + (float)(H)[4] + (float)(H)[5] + (float)(H)[6] + (float)(H)[7])

#define DOT8(H, A, B)                                                          \
    ((float)(H)[0]*(A).x + (float)(H)[1]*(A).y + (float)(H)[2]*(A).z +         \
     (float)(H)[3]*(A).w + (float)(H)[4]*(B).x + (float)(H)[5]*(B).y +         \
     (float)(H)[6]*(B).z + (float)(H)[7]*(B).w)

#define ACC8(CA, H, RS)                                                        \
    _Pragma("unroll")                                                          \
    for (int q = 0; q < 8; ++q) (CA)[q] = fmaf((float)(H)[q], (RS), (CA)[q]);

#define ACCQ8(QA, H, RS)                                                       \
    _Pragma("unroll")                                                          \
    for (int q = 0; q < 8; ++q) {                                              \
        const float tq = (float)(H)[q];                                        \
        (QA)[q] = fmaf(tq * ((SHIFT - __logf(tq)) * 0.1f), (RS), (QA)[q]);     \
    }

// Build: read D row (HBM, once), pack fp16; rows 0..3 also stored to LDS.
#define BUILD_ROW(RR, STORELDS)                                                \
    {                                                                          \
        const float4* D4 = (const float4*)(D + ((rbase + (RR)) << 10));        \
        const float4 d0 = D4[2 * lane], d1 = D4[2 * lane + 1];                 \
        h8 h0; EXP8(h0, d0, d1)                                                \
        const float4 d2 = D4[2 * (lane + 64)], d3 = D4[2 * (lane + 64) + 1];   \
        h8 h1; EXP8(h1, d2, d3)                                                \
        if (STORELDS) {                                                        \
            h8* Er = (h8*)eL[(wave << 2) + (RR)];                              \
            Er[lane] = h0; Er[lane + 64] = h1;                                 \
        }                                                                      \
        float s = SUM8(h0) + SUM8(h1);                                         \
        s = wave_allsum(s);                                                    \
        const float rs = __builtin_amdgcn_rcpf(s);                             \
        ACC8(ca0, h0, rs) ACC8(ca1, h1, rs)                                    \
        __builtin_amdgcn_sched_barrier(0);                                     \
    }

// Iter row from LDS-resident fp16 E.
#define ITER_LROW(K)                                                           \
    {                                                                          \
        const h8* Er = (const h8*)eL[(wave << 2) + (K)];                       \
        const h8 h0 = Er[lane], h1 = Er[lane + 64];                            \
        const float4 g0 = evb4[lane],        g1 = evb4[64 + lane];             \
        const float4 g2 = evb4[128 + lane],  g3 = evb4[192 + lane];            \
        float s = DOT8(h0, g0, g1) + DOT8(h1, g2, g3);                         \
        s = wave_allsum(s);                                                    \
        const float rs = __builtin_amdgcn_rcpf(s);                             \
        ACC8(ca0, h0, rs) ACC8(ca1, h1, rs)                                    \
        if (last) { ACCQ8(qa0, h0, rs) ACCQ8(qa1, h1, rs) }                    \
        __builtin_amdgcn_sched_barrier(0);                                     \
    }

// Iter row recomputed from D (L2/LLC-resident now that nothing flushes L2).
#define ITER_DROW(RR)                                                          \
    {                                                                          \
        const float4* D4 = (const float4*)(D + ((rbase + (RR)) << 10));        \
        const float4 d0 = D4[2 * lane], d1 = D4[2 * lane + 1];                 \
        h8 h0; EXP8(h0, d0, d1)                                                \
        const float4 d2 = D4[2 * (lane + 64)], d3 = D4[2 * (lane + 64) + 1];   \
        h8 h1; EXP8(h1, d2, d3)                                                \
        const float4 g0 = evb4[lane],        g1 = evb4[64 + lane];             \
        const float4 g2 = evb4[128 + lane],  g3 = evb4[192 + lane];            \
        float s = DOT8(h0, g0, g1) + DOT8(h1, g2, g3);                         \
        s = wave_allsum(s);                                                    \
        const float rs = __builtin_amdgcn_rcpf(s);                             \
        ACC8(ca0, h0, rs) ACC8(ca1, h1, rs)                                    \
        if (last) { ACCQ8(qa0, h0, rs) ACCQ8(qa1, h1, rs) }                    \
        __builtin_amdgcn_sched_barrier(0);                                     \
    }

__global__ void __attribute__((amdgpu_flat_work_group_size(1024, 1024)))
__attribute__((amdgpu_waves_per_eu(4, 4)))
sinkhorn_persist(const float* __restrict__ D, float* __restrict__ Pg,
                 float* __restrict__ Qg, unsigned* __restrict__ ctr,
                 float* __restrict__ out) {
    __shared__ __align__(16) _Float16 eL[NWAVE * 4][NMAT];        // 128 KB
    __shared__ float4 sbuf[1024];                                 // 16 KB
    __shared__ float4 evb4[NMAT / 4];                             // 4 KB (permuted)
    float* evb = (float*)evb4;

    const int b = blockIdx.x;
    const int bb = b >> 3, slab = b & 7;       // batch, row-slab within batch
    const int tid = threadIdx.x;
    const int wave = tid >> 6, lane = tid & 63;
    const size_t rbase = ((size_t)bb << 10) + (slab << 7) + (wave << 3);

    f8 ca0, ca1, qa0, qa1;

#pragma unroll 1
    for (int it = 0; it < N_ITERS; ++it) {
        const bool last = (it == N_ITERS - 1);
#pragma unroll
        for (int q = 0; q < 8; ++q) { ca0[q] = 0.f; ca1[q] = 0.f; }
        if (last) {
#pragma unroll
            for (int q = 0; q < 8; ++q) { qa0[q] = 0.f; qa1[q] = 0.f; }
        }

        if (it == 0) {
            // Build: read D (HBM once), stage rows 0..3 as fp16 in LDS,
            // iteration 1 (ev == 1) on the fly.
            BUILD_ROW(0, 1)
            BUILD_ROW(1, 1)
            BUILD_ROW(2, 1)
            BUILD_ROW(3, 1)
            BUILD_ROW(4, 0)
            BUILD_ROW(5, 0)
            BUILD_ROW(6, 0)
            BUILD_ROW(7, 0)
        } else {
            ITER_LROW(0)
            ITER_LROW(1)
            ITER_LROW(2)
            ITER_LROW(3)
            ITER_DROW(4)
            ITER_DROW(5)
            ITER_DROW(6)
            ITER_DROW(7)
        }

        // Block-level column reduction -> one 4 KB coherent partial per block.
        const int par = it & 1;   // parity double-buffer (no 2nd barrier needed)
        const float cs = stage_colsum(ca0, ca1, sbuf, wave, lane, tid);
        cstore(&Pg[((par * NBLK + b) << 10) + tid], cs);
        if (last) {
            const float qs = stage_colsum(qa0, qa1, sbuf, wave, lane, tid);
            cstore(&Qg[(b << 10) + tid], qs);
            if (b == 0 && tid == 0) cstore(out, 0.f);   // arm final atomics
        }

        grid_barrier(&ctr[it], tid);

        if (!last) {
            // Redundant per-block ev: gather this batch's 8 partials (coherent).
            const float* Pb = Pg + ((par * NBLK + (bb << 3)) << 10) + tid;
            float s8 = 0.f;
#pragma unroll
            for (int j = 0; j < 8; ++j) s8 += cload(&Pb[j << 10]);
            const float evv = 1.0f / s8;
            const int rem = tid & 511, lt = rem >> 3, ut = rem & 7;
            const int ht = ((tid >> 9) << 1) + (ut >> 2), rt = ut & 3;
            evb[(((ht << 6) + lt) << 2) + rt] = evv;
            __syncthreads();               // evb ready for next iteration
        } else if (slab == 0) {
            // loss = mean_b sum_m (sum_j Q[j][m]) / (sum_j P[j][m])
            const float* Pb = Pg + ((par * NBLK + (bb << 3)) << 10) + tid;
            const float* Qb = Qg + (((bb << 3)) << 10) + tid;
            float s8 = 0.f, q8 = 0.f;
#pragma unroll
            for (int j = 0; j < 8; ++j) {
                s8 += cload(&Pb[j << 10]);
                q8 += cload(&Qb[j << 10]);
            }
            float c = q8 / s8;
            c = wave_allsum(c);
            if (lane == 0) ((float*)sbuf)[wave] = c;
            __syncthreads();
            if (tid == 0) {
                float tot = 0.f;
#pragma unroll
                for (int w = 0; w < NWAVE; ++w) tot += ((float*)sbuf)[w];
                atomicAdd(out, tot * (1.0f / (float)BATCH));
            }
        }
    }
}

extern "C" void kernel_launch(void* const* d_in, const int* in_sizes, int n_in,
                              void* d_out, int out_size, void* d_ws, size_t ws_size,
                              hipStream_t stream) {
    const float* D = (const float*)d_in[0];
    float* out = (float*)d_out;

    unsigned* ctr = (unsigned*)d_ws;                    // 64 slots (zeroed below)
    float* Pg = (float*)((char*)d_ws + 1024);           // [2][256][1024] f32 = 2 MB
    float* Qg = Pg + 2 * NBLK * NMAT;                   // [256][1024] f32 = 1 MB

    init_ctr<<<1, 64, 0, stream>>>(ctr);
    sinkhorn_persist<<<NBLK, NWAVE * 64, 0, stream>>>(D, Pg, Qg, ctr, out);
}